// Round 5
// baseline (408.681 us; speedup 1.0000x reference)
//
#include <hip/hip_runtime.h>
#include <hip/hip_bf16.h>

// out[i,f] = a[f]*x[i,f] + b[f], a/b per group of 32 features.
// x: [2097152, 128] fp32 = 1 GiB in + 1 GiB out -> pure HBM-streaming.
// Round 5: block-contiguous ownership. Each block owns one contiguous
// ~512 KiB range and streams it sequentially with the 4x-adjacent unroll
// (Round 4's win: contiguous 16 KiB chunk per block-iter, 443->396 us).
// Consecutive iterations now continue at consecutive addresses -> each CU
// emits one long sequential read stream + one long sequential write stream.

typedef float f4 __attribute__((ext_vector_type(4)));

#define BLOCK 256
#define CHUNK (4LL * BLOCK)   // 1024 f4 = 16 KiB per block-iteration

__global__ __launch_bounds__(BLOCK) void normalize_kernel(
    const f4* __restrict__ x,
    const float* __restrict__ x_min,
    const float* __restrict__ x_max,
    const float* __restrict__ u,
    const float* __restrict__ l,
    f4* __restrict__ out,
    long long n4,
    long long per_block)   // multiple of CHUNK
{
    const int tid = threadIdx.x;
    const long long start = (long long)blockIdx.x * per_block;
    if (start >= n4) return;
    long long end = start + per_block;
    if (end > n4) end = n4;

    // start is a multiple of 1024 -> (idx & 31) == (tid & 31):
    // group invariant per thread, hoist scale/shift.
    const int g = (tid & 31) >> 3;
    const float s = (u[g] - l[g]) / (x_max[g] - x_min[g]);
    const float b = l[g] - x_min[g] * s;

    long long i = start + tid;
    for (; i + 3 * BLOCK < end; i += CHUNK) {
        f4 v0 = x[i];
        f4 v1 = x[i + 1 * BLOCK];
        f4 v2 = x[i + 2 * BLOCK];
        f4 v3 = x[i + 3 * BLOCK];
        f4 o0, o1, o2, o3;
        #pragma unroll
        for (int k = 0; k < 4; ++k) {
            o0[k] = fmaf(s, v0[k], b);
            o1[k] = fmaf(s, v1[k], b);
            o2[k] = fmaf(s, v2[k], b);
            o3[k] = fmaf(s, v3[k], b);
        }
        out[i]             = o0;
        out[i + 1 * BLOCK] = o1;
        out[i + 2 * BLOCK] = o2;
        out[i + 3 * BLOCK] = o3;
    }
    // Tail (not taken for the bench shape: per_block divides n4 exactly).
    for (; i < end; i += BLOCK) {
        f4 v = x[i];
        f4 o;
        #pragma unroll
        for (int k = 0; k < 4; ++k) o[k] = fmaf(s, v[k], b);
        out[i] = o;
    }
}

extern "C" void kernel_launch(void* const* d_in, const int* in_sizes, int n_in,
                              void* d_out, int out_size, void* d_ws, size_t ws_size,
                              hipStream_t stream) {
    const f4*    x     = (const f4*)d_in[0];
    const float* x_min = (const float*)d_in[1];
    const float* x_max = (const float*)d_in[2];
    const float* u     = (const float*)d_in[3];
    const float* l     = (const float*)d_in[4];
    f4* out = (f4*)d_out;

    const long long n4 = (long long)out_size / 4;

    const int grid = 2048;  // 8 blocks/CU on 256 CUs
    // Contiguous per-block range, rounded up to a multiple of CHUNK (16 KiB)
    // to keep chunk alignment and per-thread group invariance.
    long long per_block = (n4 + grid - 1) / grid;
    per_block = ((per_block + CHUNK - 1) / CHUNK) * CHUNK;

    normalize_kernel<<<grid, BLOCK, 0, stream>>>(x, x_min, x_max, u, l, out,
                                                 n4, per_block);
}

// Round 6
// 407.241 us; speedup vs baseline: 1.0035x; 1.0035x over previous
//
#include <hip/hip_runtime.h>
#include <hip/hip_bf16.h>

// out[i,f] = a[f]*x[i,f] + b[f], a/b per group of 32 features.
// x: [2097152, 128] fp32 = 1 GiB in + 1 GiB out -> pure HBM-streaming.
// Round 6: Round 4's winning shape (grid-stride, 16 KiB contiguous chunk
// per block-iter, lockstep window) + software pipeline 1 chunk ahead:
// issue chunk k+1's 4 loads BEFORE chunk k's 4 stores, using a second
// register set, so loads never wait behind the previous stores' vmcnt.
// (R5 block-contiguous ownership regressed: 2048 drifting streams beat
// by the lockstep 32 MiB window. R2 nt regressed. R3 strided unroll
// regressed. R4 = 396 us = 5.42 TB/s.)

typedef float f4 __attribute__((ext_vector_type(4)));

#define BLOCK 256
#define CHUNK (4LL * BLOCK)   // 1024 f4 = 16 KiB per block-iteration

__global__ __launch_bounds__(BLOCK) void normalize_kernel(
    const f4* __restrict__ x,
    const float* __restrict__ x_min,
    const float* __restrict__ x_max,
    const float* __restrict__ u,
    const float* __restrict__ l,
    f4* __restrict__ out,
    long long n4)
{
    const int tid = threadIdx.x;
    const long long gstride = (long long)gridDim.x * CHUNK;
    long long i = (long long)blockIdx.x * CHUNK + tid;

    // chunk starts are multiples of 1024 -> (idx & 31) == (tid & 31):
    // group invariant per thread, hoist scale/shift.
    const int g = (tid & 31) >> 3;
    const float s = (u[g] - l[g]) / (x_max[g] - x_min[g]);
    const float b = l[g] - x_min[g] * s;

    if (i + 3 * BLOCK < n4) {
        // Prologue: load chunk 0.
        f4 v0 = x[i];
        f4 v1 = x[i + 1 * BLOCK];
        f4 v2 = x[i + 2 * BLOCK];
        f4 v3 = x[i + 3 * BLOCK];

        long long next = i + gstride;
        for (; next + 3 * BLOCK < n4; next += gstride) {
            // Issue next chunk's loads first (independent register set).
            f4 w0 = x[next];
            f4 w1 = x[next + 1 * BLOCK];
            f4 w2 = x[next + 2 * BLOCK];
            f4 w3 = x[next + 3 * BLOCK];
            // Compute + store current chunk (loads already complete).
            f4 o0, o1, o2, o3;
            #pragma unroll
            for (int k = 0; k < 4; ++k) {
                o0[k] = fmaf(s, v0[k], b);
                o1[k] = fmaf(s, v1[k], b);
                o2[k] = fmaf(s, v2[k], b);
                o3[k] = fmaf(s, v3[k], b);
            }
            out[i]             = o0;
            out[i + 1 * BLOCK] = o1;
            out[i + 2 * BLOCK] = o2;
            out[i + 3 * BLOCK] = o3;
            i = next;
            v0 = w0; v1 = w1; v2 = w2; v3 = w3;
        }
        // Epilogue: final full chunk.
        f4 o0, o1, o2, o3;
        #pragma unroll
        for (int k = 0; k < 4; ++k) {
            o0[k] = fmaf(s, v0[k], b);
            o1[k] = fmaf(s, v1[k], b);
            o2[k] = fmaf(s, v2[k], b);
            o3[k] = fmaf(s, v3[k], b);
        }
        out[i]             = o0;
        out[i + 1 * BLOCK] = o1;
        out[i + 2 * BLOCK] = o2;
        out[i + 3 * BLOCK] = o3;
        i += gstride;
    }
    // Tail (not taken for the bench shape: n4 is an exact multiple of gstride).
    for (; i < n4; i += BLOCK) {
        f4 v = x[i];
        f4 o;
        #pragma unroll
        for (int k = 0; k < 4; ++k) o[k] = fmaf(s, v[k], b);
        out[i] = o;
    }
}

extern "C" void kernel_launch(void* const* d_in, const int* in_sizes, int n_in,
                              void* d_out, int out_size, void* d_ws, size_t ws_size,
                              hipStream_t stream) {
    const f4*    x     = (const f4*)d_in[0];
    const float* x_min = (const float*)d_in[1];
    const float* x_max = (const float*)d_in[2];
    const float* u     = (const float*)d_in[3];
    const float* l     = (const float*)d_in[4];
    f4* out = (f4*)d_out;

    const long long n4 = (long long)out_size / 4;

    int grid = 2048;  // 8 blocks/CU on 256 CUs; lockstep 32 MiB window/sweep
    long long needed = (n4 + CHUNK - 1) / CHUNK;
    if (needed < grid) grid = (int)(needed > 0 ? needed : 1);

    normalize_kernel<<<grid, BLOCK, 0, stream>>>(x, x_min, x_max, u, l, out, n4);
}

// Round 7
// 383.570 us; speedup vs baseline: 1.0655x; 1.0617x over previous
//
#include <hip/hip_runtime.h>
#include <hip/hip_bf16.h>

// out[i,f] = a[f]*x[i,f] + b[f], a/b per group of 32 features.
// x: [2097152, 128] fp32 = 1 GiB in + 1 GiB out -> pure HBM-streaming.
// Round 7: one-shot exact-fit grid. Each block = exactly ONE contiguous
// 16 KiB chunk (R4's winning chunk shape), NO grid-stride loop: 65536
// blocks dispatched in address order -> perfectly ordered chip-wide sweep,
// wave churn sustains in-flight depth, zero loop/branch overhead.
// History: R1 simple loop 443; R2 nt 485; R3 strided unroll 468;
// R4 adjacent-chunk loop 396 (best); R5 block-contiguous 409;
// R6 sw-pipeline 407.

typedef float f4 __attribute__((ext_vector_type(4)));

#define BLOCK 256
#define CHUNK (4LL * BLOCK)   // 1024 f4 = 16 KiB per block

__global__ __launch_bounds__(BLOCK) void normalize_kernel(
    const f4* __restrict__ x,
    const float* __restrict__ x_min,
    const float* __restrict__ x_max,
    const float* __restrict__ u,
    const float* __restrict__ l,
    f4* __restrict__ out,
    long long n4)
{
    const int tid = threadIdx.x;
    const long long i = (long long)blockIdx.x * CHUNK + tid;

    // chunk base is a multiple of 1024 -> (idx & 31) == (tid & 31):
    // group invariant per thread.
    const int g = (tid & 31) >> 3;
    const float s = (u[g] - l[g]) / (x_max[g] - x_min[g]);
    const float b = l[g] - x_min[g] * s;

    if (i + 3 * BLOCK < n4) {
        // Full chunk (the only path for the bench shape).
        f4 v0 = x[i];
        f4 v1 = x[i + 1 * BLOCK];
        f4 v2 = x[i + 2 * BLOCK];
        f4 v3 = x[i + 3 * BLOCK];
        f4 o0, o1, o2, o3;
        #pragma unroll
        for (int k = 0; k < 4; ++k) {
            o0[k] = fmaf(s, v0[k], b);
            o1[k] = fmaf(s, v1[k], b);
            o2[k] = fmaf(s, v2[k], b);
            o3[k] = fmaf(s, v3[k], b);
        }
        out[i]             = o0;
        out[i + 1 * BLOCK] = o1;
        out[i + 2 * BLOCK] = o2;
        out[i + 3 * BLOCK] = o3;
    } else {
        // Partial chunk tail (not taken for the bench shape).
        for (long long j = i; j < n4; j += BLOCK) {
            f4 v = x[j];
            f4 o;
            #pragma unroll
            for (int k = 0; k < 4; ++k) o[k] = fmaf(s, v[k], b);
            out[j] = o;
        }
    }
}

extern "C" void kernel_launch(void* const* d_in, const int* in_sizes, int n_in,
                              void* d_out, int out_size, void* d_ws, size_t ws_size,
                              hipStream_t stream) {
    const f4*    x     = (const f4*)d_in[0];
    const float* x_min = (const float*)d_in[1];
    const float* x_max = (const float*)d_in[2];
    const float* u     = (const float*)d_in[3];
    const float* l     = (const float*)d_in[4];
    f4* out = (f4*)d_out;

    const long long n4 = (long long)out_size / 4;

    // Exact-fit: one 16 KiB chunk per block, dispatched in address order.
    long long grid = (n4 + CHUNK - 1) / CHUNK;   // 65536 for the bench shape
    if (grid < 1) grid = 1;

    normalize_kernel<<<(int)grid, BLOCK, 0, stream>>>(x, x_min, x_max, u, l,
                                                      out, n4);
}